// Round 1
// baseline (653.315 us; speedup 1.0000x reference)
//
#include <hip/hip_runtime.h>
#include <math.h>

// Problem constants
// B=8, T=2048 -> M = 16384 rows; V=4096; C=128; 2NB=128; NOPS=8
#define M_TOT 16384
#define V_DIM 4096
#define C_DIM 128

typedef __bf16 bf16;
typedef __bf16 bf16x8 __attribute__((ext_vector_type(8)));
typedef float f32x4 __attribute__((ext_vector_type(4)));

__device__ inline f32x4 zero4() { f32x4 z; z[0]=0.f; z[1]=0.f; z[2]=0.f; z[3]=0.f; return z; }

// fp32 -> bf16 round-to-nearest-even
__device__ inline bf16 f2bf(float f) {
  union { float f; unsigned u; } a; a.f = f;
  unsigned r = (a.u + 0x7FFFu + ((a.u >> 16) & 1u)) >> 16;
  union { unsigned short s; bf16 b; } o; o.s = (unsigned short)r;
  return o.b;
}

__device__ inline bf16x8 cvt8(float4 a, float4 b) {
  bf16x8 r;
  r[0]=f2bf(a.x); r[1]=f2bf(a.y); r[2]=f2bf(a.z); r[3]=f2bf(a.w);
  r[4]=f2bf(b.x); r[5]=f2bf(b.y); r[6]=f2bf(b.z); r[7]=f2bf(b.w);
  return r;
}

// ---------------------------------------------------------------------------
// k_read: RT[c][v] = softmax_v( basis[v,:] . read_coeffs[c,:] )   (bf16)
// one block per column c; logits for all 4096 v live in LDS
// ---------------------------------------------------------------------------
__global__ __launch_bounds__(256) void k_read(const float* __restrict__ basis,
                                              const float* __restrict__ rc,
                                              bf16* __restrict__ RT) {
  const int c = blockIdx.x;
  const int t = threadIdx.x;
  __shared__ __align__(16) float coeff[128];
  __shared__ float logits[4096];
  __shared__ float red[256];
  if (t < 128) coeff[t] = rc[c * 128 + t];
  __syncthreads();
  float lmax = -3.0e38f;
  for (int v = t; v < V_DIM; v += 256) {
    const float4* br = (const float4*)(basis + v * 128);
    const float4* cr = (const float4*)coeff;
    float s = 0.f;
#pragma unroll 8
    for (int k = 0; k < 32; k++) {
      float4 b4 = br[k]; float4 c4 = cr[k];
      s += b4.x * c4.x; s += b4.y * c4.y; s += b4.z * c4.z; s += b4.w * c4.w;
    }
    logits[v] = s;
    lmax = fmaxf(lmax, s);
  }
  red[t] = lmax;
  __syncthreads();
  for (int off = 128; off > 0; off >>= 1) {
    if (t < off) red[t] = fmaxf(red[t], red[t + off]);
    __syncthreads();
  }
  const float gmax = red[0];
  __syncthreads();
  float lsum = 0.f;
  for (int v = t; v < V_DIM; v += 256) {
    float e = __expf(logits[v] - gmax);
    logits[v] = e;
    lsum += e;
  }
  red[t] = lsum;
  __syncthreads();
  for (int off = 128; off > 0; off >>= 1) {
    if (t < off) red[t] += red[t + off];
    __syncthreads();
  }
  const float inv = 1.f / red[0];
  for (int v = t; v < V_DIM; v += 256)
    RT[c * V_DIM + v] = f2bf(logits[v] * inv);
}

// ---------------------------------------------------------------------------
// k_write: W2[v][c] = basis[v,:] . write_coeffs[c,:]   (bf16, natural layout)
// one block per v
// ---------------------------------------------------------------------------
__global__ __launch_bounds__(128) void k_write(const float* __restrict__ basis,
                                               const float* __restrict__ wc,
                                               bf16* __restrict__ W2) {
  const int v = blockIdx.x;
  const int c = threadIdx.x;
  __shared__ __align__(16) float brow[128];
  brow[c] = basis[v * 128 + c];
  __syncthreads();
  const float4* cr = (const float4*)(wc + c * 128);
  const float4* br = (const float4*)brow;
  float s = 0.f;
#pragma unroll 8
  for (int k = 0; k < 32; k++) {
    float4 a = br[k], b = cr[k];
    s += a.x * b.x; s += a.y * b.y; s += a.z * b.z; s += a.w * b.w;
  }
  W2[v * 128 + c] = f2bf(s);
}

// ---------------------------------------------------------------------------
// k_ops: WTO[i][n][k] = op_weights[i][k][n]   (bf16 transpose)
// ---------------------------------------------------------------------------
__global__ __launch_bounds__(256) void k_ops(const float* __restrict__ opw,
                                             bf16* __restrict__ WTO) {
  int idx = blockIdx.x * 256 + threadIdx.x;  // 131072 total
  int i = idx >> 14, rem = idx & 16383, n = rem >> 7, k = rem & 127;
  WTO[idx] = f2bf(opw[(i << 14) + k * 128 + n]);
}

// ---------------------------------------------------------------------------
// k_gemm1: VAL[m][c] = sum_v x[m][v] * RT[c][v]    (values = x @ read_w)
// block: 64 rows x 128 cols, BK=64, 4 waves, 16x16x32 bf16 MFMA
// ---------------------------------------------------------------------------
__global__ __launch_bounds__(256) void k_gemm1(const float* __restrict__ x,
                                               const bf16* __restrict__ RT,
                                               bf16* __restrict__ val) {
  __shared__ __align__(16) bf16 Asm[64][72];   // pad 64->72 (2-way conflicts, free)
  __shared__ __align__(16) bf16 Bsm[128][72];
  const int t = threadIdx.x;
  const int m0 = blockIdx.x * 64;
  const int lane = t & 63, wave = t >> 6;
  const int fm = lane & 15, quad = lane >> 4;

  f32x4 acc[8];
#pragma unroll
  for (int i = 0; i < 8; i++) acc[i] = zero4();

  const int ar = t >> 2, ac = (t & 3) * 16;   // A: 16 fp32 per thread
  const int br = t >> 1, bc = (t & 1) * 32;   // B: 32 bf16 per thread
  const float* xp = x + (size_t)(m0 + ar) * V_DIM + ac;
  const bf16* bp = RT + br * V_DIM + bc;

  for (int k0 = 0; k0 < V_DIM; k0 += 64) {
    float4 a0 = *(const float4*)(xp + k0);
    float4 a1 = *(const float4*)(xp + k0 + 4);
    float4 a2 = *(const float4*)(xp + k0 + 8);
    float4 a3 = *(const float4*)(xp + k0 + 12);
    uint4 b0 = *(const uint4*)(bp + k0);
    uint4 b1 = *(const uint4*)(bp + k0 + 8);
    uint4 b2 = *(const uint4*)(bp + k0 + 16);
    uint4 b3 = *(const uint4*)(bp + k0 + 24);
    __syncthreads();   // previous iter's fragment reads done
    *(bf16x8*)&Asm[ar][ac]     = cvt8(a0, a1);
    *(bf16x8*)&Asm[ar][ac + 8] = cvt8(a2, a3);
    *(uint4*)&Bsm[br][bc]      = b0;
    *(uint4*)&Bsm[br][bc + 8]  = b1;
    *(uint4*)&Bsm[br][bc + 16] = b2;
    *(uint4*)&Bsm[br][bc + 24] = b3;
    __syncthreads();
    bf16x8 af0 = *(const bf16x8*)&Asm[wave * 16 + fm][quad * 8];
    bf16x8 af1 = *(const bf16x8*)&Asm[wave * 16 + fm][32 + quad * 8];
#pragma unroll
    for (int nt = 0; nt < 8; nt++) {
      bf16x8 bf0 = *(const bf16x8*)&Bsm[nt * 16 + fm][quad * 8];
      bf16x8 bf1 = *(const bf16x8*)&Bsm[nt * 16 + fm][32 + quad * 8];
      acc[nt] = __builtin_amdgcn_mfma_f32_16x16x32_bf16(af0, bf0, acc[nt], 0, 0, 0);
      acc[nt] = __builtin_amdgcn_mfma_f32_16x16x32_bf16(af1, bf1, acc[nt], 0, 0, 0);
    }
  }
  // C/D layout: col = lane&15, row = quad*4 + r
#pragma unroll
  for (int nt = 0; nt < 8; nt++)
#pragma unroll
    for (int r = 0; r < 4; r++) {
      int row = m0 + wave * 16 + quad * 4 + r;
      val[row * 128 + nt * 16 + fm] = f2bf(acc[nt][r]);
    }
}

// ---------------------------------------------------------------------------
// op bank
// ---------------------------------------------------------------------------
__device__ inline float apply_nonlin(int i, float v) {
  switch (i) {
    case 0: return v;
    case 1: return fmaxf(v, 0.f);
    case 2: return 0.5f * v * (1.f + erff(v * 0.70710678118654752f));
    case 3: return v * v;
    case 4: return -v;
    case 5: return fabsf(v);
    case 6: return tanhf(v);
    default: return 1.f / (1.f + __expf(-v));
  }
}

__global__ __launch_bounds__(256) void k_opbank(const bf16* __restrict__ val,
                                                const bf16* __restrict__ WTO,
                                                const float* __restrict__ op_logits,
                                                const float* __restrict__ op_biases,
                                                bf16* __restrict__ val2) {
  __shared__ __align__(16) bf16 Asm[64][136];   // K=128 pad->136
  __shared__ __align__(16) bf16 Bsm[128][136];
  const int t = threadIdx.x;
  const int m0 = blockIdx.x * 64;
  const int lane = t & 63, wave = t >> 6;
  const int fm = lane & 15, quad = lane >> 4;

  // softmax over the 8 op logits, in-register
  float w[8];
  {
    float lm = -3.0e38f;
#pragma unroll
    for (int i = 0; i < 8; i++) { w[i] = op_logits[i]; lm = fmaxf(lm, w[i]); }
    float s = 0.f;
#pragma unroll
    for (int i = 0; i < 8; i++) { w[i] = __expf(w[i] - lm); s += w[i]; }
    float inv = 1.f / s;
#pragma unroll
    for (int i = 0; i < 8; i++) w[i] *= inv;
  }

  {  // stage A once: 64 x 128 bf16
    const int row = t >> 2, off = (t & 3) * 32;
    const uint4* p = (const uint4*)(val + (m0 + row) * 128 + off);
    uint4 q0 = p[0], q1 = p[1], q2 = p[2], q3 = p[3];
    uint4* d = (uint4*)&Asm[row][off];
    d[0] = q0; d[1] = q1; d[2] = q2; d[3] = q3;
  }
  __syncthreads();
  bf16x8 af[4];
#pragma unroll
  for (int kk = 0; kk < 4; kk++)
    af[kk] = *(const bf16x8*)&Asm[wave * 16 + fm][kk * 32 + quad * 8];

  f32x4 res[8];
#pragma unroll
  for (int nt = 0; nt < 8; nt++) res[nt] = zero4();

  const int brow = t >> 1, boff = (t & 1) * 64;
  for (int i = 0; i < 8; i++) {
    __syncthreads();  // previous op's B reads done
    {
      const uint4* p = (const uint4*)(WTO + i * 16384 + brow * 128 + boff);
      uint4* d = (uint4*)&Bsm[brow][boff];
#pragma unroll
      for (int j = 0; j < 8; j++) d[j] = p[j];
    }
    __syncthreads();
#pragma unroll
    for (int nt = 0; nt < 8; nt++) {
      f32x4 h = zero4();
#pragma unroll
      for (int kk = 0; kk < 4; kk++) {
        bf16x8 bfr = *(const bf16x8*)&Bsm[nt * 16 + fm][kk * 32 + quad * 8];
        h = __builtin_amdgcn_mfma_f32_16x16x32_bf16(af[kk], bfr, h, 0, 0, 0);
      }
      float bias = op_biases[i * 128 + nt * 16 + fm];
#pragma unroll
      for (int r = 0; r < 4; r++) {
        float vv = h[r] + bias;
        res[nt][r] += w[i] * apply_nonlin(i, vv);
      }
    }
  }
#pragma unroll
  for (int nt = 0; nt < 8; nt++)
#pragma unroll
    for (int r = 0; r < 4; r++) {
      int row = m0 + wave * 16 + quad * 4 + r;
      val2[row * 128 + nt * 16 + fm] = f2bf(res[nt][r]);
    }
}

// ---------------------------------------------------------------------------
// k_gemm2: out[m][v] = scale * sum_c VAL2[m][c] * W2[v][c]
// block: 64 rows x 128 v-cols, K=128 single stage
// ---------------------------------------------------------------------------
__global__ __launch_bounds__(256) void k_gemm2(const bf16* __restrict__ val2,
                                               const bf16* __restrict__ W2,
                                               const float* __restrict__ p_scale,
                                               float* __restrict__ out) {
  __shared__ __align__(16) bf16 Asm[64][136];
  __shared__ __align__(16) bf16 Bsm[128][136];
  const int t = threadIdx.x;
  const int m0 = (blockIdx.x >> 5) * 64;   // 256 m-tiles
  const int n0 = (blockIdx.x & 31) * 128;  // 32 n-tiles
  const int lane = t & 63, wave = t >> 6;
  const int fm = lane & 15, quad = lane >> 4;

  {
    const int row = t >> 2, off = (t & 3) * 32;
    const uint4* p = (const uint4*)(val2 + (m0 + row) * 128 + off);
    uint4* d = (uint4*)&Asm[row][off];
#pragma unroll
    for (int j = 0; j < 4; j++) d[j] = p[j];
  }
  {
    const int row = t >> 1, off = (t & 1) * 64;
    const uint4* p = (const uint4*)(W2 + (n0 + row) * 128 + off);
    uint4* d = (uint4*)&Bsm[row][off];
#pragma unroll
    for (int j = 0; j < 8; j++) d[j] = p[j];
  }
  __syncthreads();

  const float scale = *p_scale;
  bf16x8 af[4];
#pragma unroll
  for (int kk = 0; kk < 4; kk++)
    af[kk] = *(const bf16x8*)&Asm[wave * 16 + fm][kk * 32 + quad * 8];

#pragma unroll
  for (int nt = 0; nt < 8; nt++) {
    f32x4 acc = zero4();
#pragma unroll
    for (int kk = 0; kk < 4; kk++) {
      bf16x8 bfr = *(const bf16x8*)&Bsm[nt * 16 + fm][kk * 32 + quad * 8];
      acc = __builtin_amdgcn_mfma_f32_16x16x32_bf16(af[kk], bfr, acc, 0, 0, 0);
    }
#pragma unroll
    for (int r = 0; r < 4; r++) {
      int row = m0 + wave * 16 + quad * 4 + r;
      out[(size_t)row * V_DIM + n0 + nt * 16 + fm] = acc[r] * scale;
    }
  }
}

// ---------------------------------------------------------------------------
// launch
// ---------------------------------------------------------------------------
extern "C" void kernel_launch(void* const* d_in, const int* in_sizes, int n_in,
                              void* d_out, int out_size, void* d_ws, size_t ws_size,
                              hipStream_t stream) {
  const float* x      = (const float*)d_in[0];
  const float* basis  = (const float*)d_in[1];
  const float* rc     = (const float*)d_in[2];
  const float* wc     = (const float*)d_in[3];
  const float* oplog  = (const float*)d_in[4];
  const float* opw    = (const float*)d_in[5];
  const float* opb    = (const float*)d_in[6];
  const float* oscale = (const float*)d_in[7];
  float* out = (float*)d_out;
  char* ws = (char*)d_ws;

  // workspace layout (total ~10.5 MB)
  bf16* RT   = (bf16*)(ws);                                   // 1 MB  (C,V)
  bf16* W2   = (bf16*)(ws + (1u << 20));                      // 1 MB  (V,C)
  bf16* WTO  = (bf16*)(ws + (2u << 20));                      // 256 KB (8,n,k)
  bf16* VAL  = (bf16*)(ws + (2u << 20) + (1u << 19));         // 4 MB  (M,C)
  bf16* VAL2 = (bf16*)(ws + (2u << 20) + (1u << 19) + (4u << 20));  // 4 MB

  k_read <<<C_DIM, 256, 0, stream>>>(basis, rc, RT);
  k_write<<<V_DIM, 128, 0, stream>>>(basis, wc, W2);
  k_ops  <<<512, 256, 0, stream>>>(opw, WTO);
  k_gemm1<<<M_TOT / 64, 256, 0, stream>>>(x, RT, VAL);
  k_opbank<<<M_TOT / 64, 256, 0, stream>>>(VAL, WTO, oplog, opb, VAL2);
  k_gemm2<<<(M_TOT / 64) * (V_DIM / 128), 256, 0, stream>>>(VAL2, W2, oscale, out);
}

// Round 2
// 582.600 us; speedup vs baseline: 1.1214x; 1.1214x over previous
//
#include <hip/hip_runtime.h>
#include <math.h>

// B=8, T=2048 -> M = 16384 rows; V=4096; C=128; 2NB=128; NOPS=8
#define M_TOT 16384
#define V_DIM 4096
#define C_DIM 128

typedef __bf16 bf16;
typedef __bf16 bf16x8 __attribute__((ext_vector_type(8)));
typedef float f32x4 __attribute__((ext_vector_type(4)));

__device__ inline f32x4 zero4() { f32x4 z; z[0]=0.f; z[1]=0.f; z[2]=0.f; z[3]=0.f; return z; }

__device__ inline bf16 f2bf(float f) {
  union { float f; unsigned u; } a; a.f = f;
  unsigned r = (a.u + 0x7FFFu + ((a.u >> 16) & 1u)) >> 16;
  union { unsigned short s; bf16 b; } o; o.s = (unsigned short)r;
  return o.b;
}

__device__ inline bf16x8 cvt8(float4 a, float4 b) {
  bf16x8 r;
  r[0]=f2bf(a.x); r[1]=f2bf(a.y); r[2]=f2bf(a.z); r[3]=f2bf(a.w);
  r[4]=f2bf(b.x); r[5]=f2bf(b.y); r[6]=f2bf(b.z); r[7]=f2bf(b.w);
  return r;
}

// ---------------------------------------------------------------------------
// k_logits: LT[c][v] = rc[c,:] . basis[v,:]   (fp32 out, MFMA)
// grid 32 (v-tiles of 128), block 256. M=c=128, N=v=128, K=128.
// ---------------------------------------------------------------------------
__global__ __launch_bounds__(256) void k_logits(const float* __restrict__ basis,
                                                const float* __restrict__ rc,
                                                float* __restrict__ LT) {
  __shared__ __align__(16) bf16 Asm[128][136];  // rc
  __shared__ __align__(16) bf16 Bsm[128][136];  // basis v-tile
  const int t = threadIdx.x;
  const int v0 = blockIdx.x * 128;
  const int lane = t & 63, wave = t >> 6, fm = lane & 15, quad = lane >> 4;

  {  // stage A = rc (128x128 fp32 -> bf16): 64 floats/thread
    const int row = t >> 1, c0 = (t & 1) * 64;
    const float4* p = (const float4*)(rc + row * 128 + c0);
    bf16x8* d = (bf16x8*)&Asm[row][c0];
#pragma unroll
    for (int j = 0; j < 8; j++) { float4 a = p[2*j], b = p[2*j+1]; d[j] = cvt8(a, b); }
  }
  {  // stage B = basis rows v0..v0+127
    const int row = t >> 1, c0 = (t & 1) * 64;
    const float4* p = (const float4*)(basis + (size_t)(v0 + row) * 128 + c0);
    bf16x8* d = (bf16x8*)&Bsm[row][c0];
#pragma unroll
    for (int j = 0; j < 8; j++) { float4 a = p[2*j], b = p[2*j+1]; d[j] = cvt8(a, b); }
  }
  __syncthreads();

  f32x4 acc[2][8];
#pragma unroll
  for (int m = 0; m < 2; m++)
#pragma unroll
    for (int n = 0; n < 8; n++) acc[m][n] = zero4();

#pragma unroll
  for (int kk = 0; kk < 4; kk++) {
    bf16x8 af[2];
#pragma unroll
    for (int m = 0; m < 2; m++)
      af[m] = *(const bf16x8*)&Asm[wave * 32 + m * 16 + fm][kk * 32 + quad * 8];
#pragma unroll
    for (int nt = 0; nt < 8; nt++) {
      bf16x8 bfr = *(const bf16x8*)&Bsm[nt * 16 + fm][kk * 32 + quad * 8];
#pragma unroll
      for (int m = 0; m < 2; m++)
        acc[m][nt] = __builtin_amdgcn_mfma_f32_16x16x32_bf16(af[m], bfr, acc[m][nt], 0, 0, 0);
    }
  }
#pragma unroll
  for (int m = 0; m < 2; m++)
#pragma unroll
    for (int nt = 0; nt < 8; nt++)
#pragma unroll
      for (int r = 0; r < 4; r++) {
        int c = wave * 32 + m * 16 + quad * 4 + r;
        LT[(size_t)c * V_DIM + v0 + nt * 16 + fm] = acc[m][nt][r];
      }
}

// ---------------------------------------------------------------------------
// k_softmax: RT[c][v] = softmax_v(LT[c][v])   (bf16), block per c
// ---------------------------------------------------------------------------
__global__ __launch_bounds__(256) void k_softmax(const float* __restrict__ LT,
                                                 bf16* __restrict__ RT) {
  const int c = blockIdx.x, t = threadIdx.x;
  __shared__ float red[256];
  const float* row = LT + (size_t)c * V_DIM;
  float e[16];
  float lmax = -3.0e38f;
#pragma unroll
  for (int j = 0; j < 16; j++) { e[j] = row[t + 256 * j]; lmax = fmaxf(lmax, e[j]); }
  red[t] = lmax;
  __syncthreads();
  for (int off = 128; off > 0; off >>= 1) {
    if (t < off) red[t] = fmaxf(red[t], red[t + off]);
    __syncthreads();
  }
  const float gmax = red[0];
  __syncthreads();
  float lsum = 0.f;
#pragma unroll
  for (int j = 0; j < 16; j++) { e[j] = __expf(e[j] - gmax); lsum += e[j]; }
  red[t] = lsum;
  __syncthreads();
  for (int off = 128; off > 0; off >>= 1) {
    if (t < off) red[t] += red[t + off];
    __syncthreads();
  }
  const float inv = 1.f / red[0];
#pragma unroll
  for (int j = 0; j < 16; j++)
    RT[(size_t)c * V_DIM + t + 256 * j] = f2bf(e[j] * inv);
}

// ---------------------------------------------------------------------------
// k_w2: W2[v][c] = basis[v,:] . wc[c,:]   (bf16, MFMA)  M=v tile 64, N=c=128
// ---------------------------------------------------------------------------
__global__ __launch_bounds__(256) void k_w2(const float* __restrict__ basis,
                                            const float* __restrict__ wc,
                                            bf16* __restrict__ W2) {
  __shared__ __align__(16) bf16 Asm[64][136];   // basis tile
  __shared__ __align__(16) bf16 Bsm[128][136];  // wc
  const int t = threadIdx.x;
  const int v0 = blockIdx.x * 64;
  const int lane = t & 63, wave = t >> 6, fm = lane & 15, quad = lane >> 4;

  {  // A: 64 rows x 128 -> 32 floats/thread
    const int row = t >> 2, c0 = (t & 3) * 32;
    const float4* p = (const float4*)(basis + (size_t)(v0 + row) * 128 + c0);
    bf16x8* d = (bf16x8*)&Asm[row][c0];
#pragma unroll
    for (int j = 0; j < 4; j++) { float4 a = p[2*j], b = p[2*j+1]; d[j] = cvt8(a, b); }
  }
  {  // B: wc 128x128
    const int row = t >> 1, c0 = (t & 1) * 64;
    const float4* p = (const float4*)(wc + row * 128 + c0);
    bf16x8* d = (bf16x8*)&Bsm[row][c0];
#pragma unroll
    for (int j = 0; j < 8; j++) { float4 a = p[2*j], b = p[2*j+1]; d[j] = cvt8(a, b); }
  }
  __syncthreads();

  f32x4 acc[8];
#pragma unroll
  for (int n = 0; n < 8; n++) acc[n] = zero4();
#pragma unroll
  for (int kk = 0; kk < 4; kk++) {
    bf16x8 af = *(const bf16x8*)&Asm[wave * 16 + fm][kk * 32 + quad * 8];
#pragma unroll
    for (int nt = 0; nt < 8; nt++) {
      bf16x8 bfr = *(const bf16x8*)&Bsm[nt * 16 + fm][kk * 32 + quad * 8];
      acc[nt] = __builtin_amdgcn_mfma_f32_16x16x32_bf16(af, bfr, acc[nt], 0, 0, 0);
    }
  }
#pragma unroll
  for (int nt = 0; nt < 8; nt++)
#pragma unroll
    for (int r = 0; r < 4; r++) {
      int v = v0 + wave * 16 + quad * 4 + r;
      W2[v * 128 + nt * 16 + fm] = f2bf(acc[nt][r]);
    }
}

// ---------------------------------------------------------------------------
// k_ops: WTO[i][n][k] = op_weights[i][k][n]   (bf16 transpose)
// ---------------------------------------------------------------------------
__global__ __launch_bounds__(256) void k_ops(const float* __restrict__ opw,
                                             bf16* __restrict__ WTO) {
  int idx = blockIdx.x * 256 + threadIdx.x;  // 131072 total
  int i = idx >> 14, rem = idx & 16383, n = rem >> 7, k = rem & 127;
  WTO[idx] = f2bf(opw[(i << 14) + k * 128 + n]);
}

// ---------------------------------------------------------------------------
// k_gemm1: split-K. PART[kc][m][c] = sum_{v in chunk kc} x[m][v] * RT[c][v]
// grid 1024: kc = bid&3, m-tile = bid>>2 (64 rows). BK=64. 4 blocks/CU.
// ---------------------------------------------------------------------------
__global__ __launch_bounds__(256) void k_gemm1(const float* __restrict__ x,
                                               const bf16* __restrict__ RT,
                                               bf16* __restrict__ PART) {
  __shared__ __align__(16) bf16 Asm[64][72];
  __shared__ __align__(16) bf16 Bsm[128][72];
  const int t = threadIdx.x;
  const int kc = blockIdx.x & 3;
  const int m0 = (blockIdx.x >> 2) * 64;
  const int lane = t & 63, wave = t >> 6;
  const int fm = lane & 15, quad = lane >> 4;

  f32x4 acc[8];
#pragma unroll
  for (int i = 0; i < 8; i++) acc[i] = zero4();

  const int ar = t >> 2, ac = (t & 3) * 16;
  const int br = t >> 1, bc = (t & 1) * 32;
  const float* xp = x + (size_t)(m0 + ar) * V_DIM + ac;
  const bf16* bp = RT + (size_t)br * V_DIM + bc;
  const int kbeg = kc * 1024, kend = kbeg + 1024;

  for (int k0 = kbeg; k0 < kend; k0 += 64) {
    float4 a0 = *(const float4*)(xp + k0);
    float4 a1 = *(const float4*)(xp + k0 + 4);
    float4 a2 = *(const float4*)(xp + k0 + 8);
    float4 a3 = *(const float4*)(xp + k0 + 12);
    uint4 b0 = *(const uint4*)(bp + k0);
    uint4 b1 = *(const uint4*)(bp + k0 + 8);
    uint4 b2 = *(const uint4*)(bp + k0 + 16);
    uint4 b3 = *(const uint4*)(bp + k0 + 24);
    __syncthreads();
    *(bf16x8*)&Asm[ar][ac]     = cvt8(a0, a1);
    *(bf16x8*)&Asm[ar][ac + 8] = cvt8(a2, a3);
    *(uint4*)&Bsm[br][bc]      = b0;
    *(uint4*)&Bsm[br][bc + 8]  = b1;
    *(uint4*)&Bsm[br][bc + 16] = b2;
    *(uint4*)&Bsm[br][bc + 24] = b3;
    __syncthreads();
    bf16x8 af0 = *(const bf16x8*)&Asm[wave * 16 + fm][quad * 8];
    bf16x8 af1 = *(const bf16x8*)&Asm[wave * 16 + fm][32 + quad * 8];
#pragma unroll
    for (int nt = 0; nt < 8; nt++) {
      bf16x8 bf0 = *(const bf16x8*)&Bsm[nt * 16 + fm][quad * 8];
      bf16x8 bf1 = *(const bf16x8*)&Bsm[nt * 16 + fm][32 + quad * 8];
      acc[nt] = __builtin_amdgcn_mfma_f32_16x16x32_bf16(af0, bf0, acc[nt], 0, 0, 0);
      acc[nt] = __builtin_amdgcn_mfma_f32_16x16x32_bf16(af1, bf1, acc[nt], 0, 0, 0);
    }
  }
  bf16* po = PART + (size_t)kc * (M_TOT * C_DIM);
#pragma unroll
  for (int nt = 0; nt < 8; nt++)
#pragma unroll
    for (int r = 0; r < 4; r++) {
      int row = m0 + wave * 16 + quad * 4 + r;
      po[row * 128 + nt * 16 + fm] = f2bf(acc[nt][r]);
    }
}

// ---------------------------------------------------------------------------
// op bank (sums the 4 split-K partials during A staging)
// grid 512 (m-tile 32), block 256
// ---------------------------------------------------------------------------
__device__ inline float apply_nonlin(int i, float v) {
  switch (i) {
    case 0: return v;
    case 1: return fmaxf(v, 0.f);
    case 2: return 0.5f * v * (1.f + erff(v * 0.70710678118654752f));
    case 3: return v * v;
    case 4: return -v;
    case 5: return fabsf(v);
    case 6: return tanhf(v);
    default: return 1.f / (1.f + __expf(-v));
  }
}

__global__ __launch_bounds__(256) void k_opbank(const bf16* __restrict__ PART,
                                                const bf16* __restrict__ WTO,
                                                const float* __restrict__ op_logits,
                                                const float* __restrict__ op_biases,
                                                bf16* __restrict__ val2) {
  __shared__ __align__(16) bf16 Asm[32][136];
  __shared__ __align__(16) bf16 Bsm[128][136];
  const int t = threadIdx.x;
  const int m0 = blockIdx.x * 32;
  const int lane = t & 63, wave = t >> 6;
  const int fm = lane & 15, quad = lane >> 4;
  const int mf = wave & 1, nh = wave >> 1;

  float w[8];
  {
    float lm = -3.0e38f;
#pragma unroll
    for (int i = 0; i < 8; i++) { w[i] = op_logits[i]; lm = fmaxf(lm, w[i]); }
    float s = 0.f;
#pragma unroll
    for (int i = 0; i < 8; i++) { w[i] = __expf(w[i] - lm); s += w[i]; }
    float inv = 1.f / s;
#pragma unroll
    for (int i = 0; i < 8; i++) w[i] *= inv;
  }

  {  // stage A: sum 4 bf16 partials -> bf16. 16 elems/thread.
    const int row = t >> 3, c0 = (t & 7) * 16;
    float accA[16];
#pragma unroll
    for (int j = 0; j < 16; j++) accA[j] = 0.f;
#pragma unroll
    for (int p = 0; p < 4; p++) {
      const bf16x8* q = (const bf16x8*)(PART + (size_t)p * (M_TOT * C_DIM) + (m0 + row) * 128 + c0);
      bf16x8 u0 = q[0], u1 = q[1];
#pragma unroll
      for (int j = 0; j < 8; j++) { accA[j] += (float)u0[j]; accA[8 + j] += (float)u1[j]; }
    }
    bf16x8 o0, o1;
#pragma unroll
    for (int j = 0; j < 8; j++) { o0[j] = f2bf(accA[j]); o1[j] = f2bf(accA[8 + j]); }
    *(bf16x8*)&Asm[row][c0] = o0;
    *(bf16x8*)&Asm[row][c0 + 8] = o1;
  }
  __syncthreads();

  bf16x8 af[4];
#pragma unroll
  for (int kk = 0; kk < 4; kk++)
    af[kk] = *(const bf16x8*)&Asm[mf * 16 + fm][kk * 32 + quad * 8];

  f32x4 res[4];
#pragma unroll
  for (int j = 0; j < 4; j++) res[j] = zero4();

  const int brow = t >> 1, boff = (t & 1) * 64;
  for (int i = 0; i < 8; i++) {
    __syncthreads();
    {
      const uint4* p = (const uint4*)(WTO + i * 16384 + brow * 128 + boff);
      uint4* d = (uint4*)&Bsm[brow][boff];
#pragma unroll
      for (int j = 0; j < 8; j++) d[j] = p[j];
    }
    __syncthreads();
#pragma unroll
    for (int j = 0; j < 4; j++) {
      const int nt = nh * 4 + j;
      f32x4 h = zero4();
#pragma unroll
      for (int kk = 0; kk < 4; kk++) {
        bf16x8 bfr = *(const bf16x8*)&Bsm[nt * 16 + fm][kk * 32 + quad * 8];
        h = __builtin_amdgcn_mfma_f32_16x16x32_bf16(af[kk], bfr, h, 0, 0, 0);
      }
      float bias = op_biases[i * 128 + nt * 16 + fm];
#pragma unroll
      for (int r = 0; r < 4; r++) {
        float vv = h[r] + bias;
        res[j][r] += w[i] * apply_nonlin(i, vv);
      }
    }
  }
#pragma unroll
  for (int j = 0; j < 4; j++) {
    const int nt = nh * 4 + j;
#pragma unroll
    for (int r = 0; r < 4; r++) {
      int row = m0 + mf * 16 + quad * 4 + r;
      val2[row * 128 + nt * 16 + fm] = f2bf(res[j][r]);
    }
  }
}

// ---------------------------------------------------------------------------
// k_gemm2: out[m][v] = scale * sum_c val2[m][c] * W2[v][c]
// 64x128 tile, K=128 single stage; LDS round-trip for coalesced float4 stores
// grid 8192: n-tile = bid>>8 (32), m-tile = bid&255
// ---------------------------------------------------------------------------
struct G2S { bf16 A[64][136]; bf16 B[128][136]; };
union G2U { G2S s; float C[64][132]; };

__global__ __launch_bounds__(256) void k_gemm2(const bf16* __restrict__ val2,
                                               const bf16* __restrict__ W2,
                                               const float* __restrict__ p_scale,
                                               float* __restrict__ out) {
  __shared__ __align__(16) G2U u;
  const int t = threadIdx.x;
  const int n0 = (blockIdx.x >> 8) * 128;
  const int m0 = (blockIdx.x & 255) * 64;
  const int lane = t & 63, wave = t >> 6;
  const int fm = lane & 15, quad = lane >> 4;

  {
    const int row = t >> 2, off = (t & 3) * 32;
    const uint4* p = (const uint4*)(val2 + (m0 + row) * 128 + off);
    uint4* d = (uint4*)&u.s.A[row][off];
#pragma unroll
    for (int j = 0; j < 4; j++) d[j] = p[j];
  }
  {
    const int row = t >> 1, off = (t & 1) * 64;
    const uint4* p = (const uint4*)(W2 + (n0 + row) * 128 + off);
    uint4* d = (uint4*)&u.s.B[row][off];
#pragma unroll
    for (int j = 0; j < 8; j++) d[j] = p[j];
  }
  __syncthreads();

  const float scale = *p_scale;
  bf16x8 af[4];
#pragma unroll
  for (int kk = 0; kk < 4; kk++)
    af[kk] = *(const bf16x8*)&u.s.A[wave * 16 + fm][kk * 32 + quad * 8];

  f32x4 acc[8];
#pragma unroll
  for (int nt = 0; nt < 8; nt++) {
    acc[nt] = zero4();
#pragma unroll
    for (int kk = 0; kk < 4; kk++) {
      bf16x8 bfr = *(const bf16x8*)&u.s.B[nt * 16 + fm][kk * 32 + quad * 8];
      acc[nt] = __builtin_amdgcn_mfma_f32_16x16x32_bf16(af[kk], bfr, acc[nt], 0, 0, 0);
    }
  }
  __syncthreads();  // all LDS reads done before C overwrites A/B
#pragma unroll
  for (int nt = 0; nt < 8; nt++)
#pragma unroll
    for (int r = 0; r < 4; r++)
      u.C[wave * 16 + quad * 4 + r][nt * 16 + fm] = acc[nt][r] * scale;
  __syncthreads();
#pragma unroll
  for (int j = 0; j < 8; j++) {
    int idx = t + 256 * j;
    int row = idx >> 5, c4 = idx & 31;
    float4 v = *(const float4*)&u.C[row][c4 * 4];
    *(float4*)(out + (size_t)(m0 + row) * V_DIM + n0 + c4 * 4) = v;
  }
}

// ---------------------------------------------------------------------------
// launch
// ---------------------------------------------------------------------------
extern "C" void kernel_launch(void* const* d_in, const int* in_sizes, int n_in,
                              void* d_out, int out_size, void* d_ws, size_t ws_size,
                              hipStream_t stream) {
  const float* x      = (const float*)d_in[0];
  const float* basis  = (const float*)d_in[1];
  const float* rc     = (const float*)d_in[2];
  const float* wc     = (const float*)d_in[3];
  const float* oplog  = (const float*)d_in[4];
  const float* opw    = (const float*)d_in[5];
  const float* opb    = (const float*)d_in[6];
  const float* oscale = (const float*)d_in[7];
  float* out = (float*)d_out;
  char* ws = (char*)d_ws;

  // workspace layout (~24.3 MB)
  float* LT  = (float*)(ws);                    // 2 MB   (C,V) fp32 logits
  bf16* RT   = (bf16*)(ws + 2097152);           // 1 MB   (C,V)
  bf16* W2   = (bf16*)(ws + 3145728);           // 1 MB   (V,C)
  bf16* WTO  = (bf16*)(ws + 4194304);           // 256 KB (8,n,k)
  bf16* PART = (bf16*)(ws + 4456448);           // 16 MB  (4,M,C) split-K partials
  bf16* VAL2 = (bf16*)(ws + 21233664);          // 4 MB   (M,C)

  k_logits <<<V_DIM / 128, 256, 0, stream>>>(basis, rc, LT);
  k_w2     <<<V_DIM / 64, 256, 0, stream>>>(basis, wc, W2);
  k_ops    <<<512, 256, 0, stream>>>(opw, WTO);
  k_softmax<<<C_DIM, 256, 0, stream>>>(LT, RT);
  k_gemm1  <<<(M_TOT / 64) * 4, 256, 0, stream>>>(x, RT, PART);
  k_opbank <<<M_TOT / 32, 256, 0, stream>>>(PART, WTO, oplog, opb, VAL2);
  k_gemm2  <<<(M_TOT / 64) * (V_DIM / 128), 256, 0, stream>>>(VAL2, W2, oscale, out);
}